// Round 1
// baseline (266.567 us; speedup 1.0000x reference)
//
#include <hip/hip_runtime.h>
#include <stdint.h>

typedef unsigned short u16;
typedef __attribute__((ext_vector_type(4))) short short4v;
typedef __attribute__((ext_vector_type(8))) short short8v;
typedef __attribute__((ext_vector_type(4))) float f32x4;
typedef __attribute__((address_space(1))) void gv;
typedef __attribute__((address_space(3))) void lv;

#define NTOK 32768

__device__ __forceinline__ float bf2f(u16 u){ return __uint_as_float(((uint32_t)u)<<16); }
__device__ __forceinline__ u16 f2bf(float f){
  uint32_t u = __float_as_uint(f);
  u += 0x7FFFu + ((u>>16)&1u);
  return (u16)(u>>16);
}
// RNE split (prep only)
__device__ __forceinline__ void hilo(float v, u16& h, u16& l){
  h = f2bf(v);
  l = f2bf(v - bf2f(h));
}
// truncating split (hot paths)
__device__ __forceinline__ void tsplit(float v, u16& h, u16& l){
  uint32_t b = __float_as_uint(v);
  h = (u16)(b >> 16);
  float lf = v - __uint_as_float(b & 0xFFFF0000u);
  l = (u16)(__float_as_uint(lf) >> 16);
}
__device__ __forceinline__ void tpack8(float4 a, float4 b, short8v& hi, short8v& lo){
  float v[8] = {a.x,a.y,a.z,a.w,b.x,b.y,b.z,b.w};
  #pragma unroll
  for (int i=0;i<8;++i){ u16 h,l; tsplit(v[i],h,l); hi[i]=(short)h; lo[i]=(short)l; }
}
__device__ __forceinline__ float gelu_f(float v){ return 0.5f*v*(1.0f + erff(v*0.70710678118654752440f)); }
// tanh-approx GELU (output kernel only): max abs dev from exact ~3e-4, ~8 VALU ops
__device__ __forceinline__ float gelu_t(float x){
  float u = 0.7978845608028654f*(x + 0.044715f*x*x*x);
  float t = 1.0f - 2.0f/(__expf(2.0f*u) + 1.0f);
  return 0.5f*x*(1.0f + t);
}
__device__ __forceinline__ float tanh_f(float x){ return 1.0f - 2.0f/(__expf(2.0f*x)+1.0f); }

// ---------------- K0: prep ----------------
// woB: fragment-linear B of wo^T: i = (((kt*4+cp)*16+n)*64 + ln)*8 + e
__global__ __launch_bounds__(256) void k_prep(
    const float* __restrict__ w1, const float* __restrict__ wa, const float* __restrict__ wb,
    const float* __restrict__ pos, const float* __restrict__ curv,
    const float* __restrict__ mem, const float* __restrict__ wo,
    const float* __restrict__ alpha,
    u16* __restrict__ w1s, u16* __restrict__ wah, u16* __restrict__ wbh,
    float2* __restrict__ mnw,
    u16* __restrict__ memb, u16* __restrict__ woB, u16* __restrict__ posB)
{
  int i = blockIdx.x*256 + threadIdx.x;
  if (i < 49152){ int n = i>>10, k = i&1023; u16 h,l; hilo(w1[k*48+n], h, l);
                  w1s[i] = h; w1s[49152+i] = l; return; }
  i -= 49152;
  if (i < 8192){ int u = i>>6, d = i&63; float v = (d<48) ? wa[d*128+u] : 0.f;
                 u16 h,l; hilo(v,h,l); wah[i] = h; wah[8192+i] = l; return; }
  i -= 8192;
  if (i < 6144){ int n = i>>7, u = i&127; u16 h,l; hilo(wb[u*48+n], h, l);
                 wbh[i] = h; wbh[6144+i] = l; return; }
  i -= 6144;
  if (i < 512){
    float s = 0.f;
    #pragma unroll
    for (int d=0; d<48; ++d){ float v = pos[i*48+d]; s += v*v; }
    float c2 = 0.f;
    #pragma unroll
    for (int d=0; d<16; ++d){ float v = curv[i*16+d]; c2 += v*v; }
    mnw[i] = make_float2(s, expf(-alpha[0]*sqrtf(c2)));
    return;
  }
  i -= 512;
  if (i < 131072){ memb[i] = f2bf(mem[i]); return; }
  i -= 131072;
  if (i < 262144){
    int e = i & 7, ln = (i>>3)&63, n = (i>>9)&15, cpq = (i>>13)&3, kt = i>>15;
    int col = cpq*256 + n*16 + (ln & 15);
    int k   = kt*32 + (ln >> 4)*8 + e;
    woB[i] = f2bf(wo[k*1024 + col]);
    return;
  }
  i -= 262144;
  if (i < 32768){
    int e = i & 7, ln = (i>>3)&63, n = (i>>9)&31, ks = i>>14;
    int slot = n*16 + (ln&15);
    int d = ks*32 + (ln>>4)*8 + e;
    float v = (d < 48) ? pos[slot*48 + d] : 0.f;
    u16 h,l; hilo(v,h,l);
    posB[i] = h; posB[32768+i] = l;
  }
}

// ---------------- K1: x@w1 via global_load_lds pipeline + LN(48) + GELU -> h48 ----------------
__global__ __launch_bounds__(256, 2) void k_proj(
    const float* __restrict__ x, const u16* __restrict__ w1s,
    const float* __restrict__ b1, const float* __restrict__ g1, const float* __restrict__ be1,
    float* __restrict__ hout)
{
  extern __shared__ char dynp[];
  float* xsl = (float*)dynp;                 // 3 * 4096 floats
  u16*   bsl = (u16*)(dynp + 49152);         // 2 * 6144 u16

  const int tid = threadIdx.x;
  const int lane = tid & 63, w = tid >> 6;
  const int l15 = lane & 15, l4 = lane >> 4;
  const int bm = blockIdx.x;
  const int arow = w*16 + l15;

  f32x4 acc[3];
  #pragma unroll
  for (int n=0; n<3; ++n) acc[n] = (f32x4){0.f,0.f,0.f,0.f};

  auto stage_x = [&](float* dst, int kt){
    #pragma unroll
    for (int j=0; j<4; ++j){
      int idx = (j*4 + w)*64 + lane;
      int row = idx >> 4, q = idx & 15;
      int chunk = q >> 1, half = q & 1;
      const float* src = x + (size_t)(bm*64 + row)*1024 + kt*64 + ((chunk ^ (row & 7))*8 + half*4);
      __builtin_amdgcn_global_load_lds((gv*)src, (lv*)(dst + (j*4 + w)*256), 16, 0, 0);
    }
  };
  auto stage_b = [&](u16* dst, int kt){
    #pragma unroll
    for (int j=0; j<3; ++j){
      int idx = (j*4 + w)*64 + lane;
      int hl = (idx >= 384) ? 1 : 0;
      int rr = idx - hl*384;
      int row = rr >> 3, ch = rr & 7;
      const u16* src = w1s + hl*49152 + (size_t)row*1024 + kt*64 + ((ch ^ (row & 7))*8);
      __builtin_amdgcn_global_load_lds((gv*)src, (lv*)(dst + (j*4 + w)*512), 16, 0, 0);
    }
  };
  auto mfma_from = [&](const float* xb, const u16* bb){
    #pragma unroll
    for (int kq=0; kq<2; ++kq){
      int chunk = kq*4 + l4;
      int phys = chunk ^ (arow & 7);
      const float* xa = xb + arow*64 + phys*8;
      float4 a0 = *(const float4*)xa;
      float4 a1 = *(const float4*)(xa + 4);
      short8v ah, al; tpack8(a0, a1, ah, al);
      #pragma unroll
      for (int n=0; n<3; ++n){
        int brow = n*16 + l15;
        int bcx = chunk ^ (brow & 7);
        short8v bh = *(const short8v*)(bb + brow*64 + bcx*8);
        short8v bl = *(const short8v*)(bb + 3072 + brow*64 + bcx*8);
        acc[n] = __builtin_amdgcn_mfma_f32_16x16x32_bf16(ah, bh, acc[n], 0, 0, 0);
        acc[n] = __builtin_amdgcn_mfma_f32_16x16x32_bf16(ah, bl, acc[n], 0, 0, 0);
        acc[n] = __builtin_amdgcn_mfma_f32_16x16x32_bf16(al, bh, acc[n], 0, 0, 0);
      }
    }
  };

  float* x0 = xsl;         float* x1 = xsl + 4096;  float* x2 = xsl + 8192;
  u16*   b0 = bsl;         u16*   b1b = bsl + 6144;

  stage_b(b0, 0);
  stage_x(x0, 0);
  stage_x(x1, 1);

  float* xc = x0; float* xn = x1; float* xn2 = x2;
  u16* bc = b0;  u16* bn = b1b;

  for (int kt = 0; kt < 15; ++kt){
    asm volatile("s_waitcnt vmcnt(4)" ::: "memory");
    __builtin_amdgcn_s_barrier();
    __builtin_amdgcn_sched_barrier(0);
    mfma_from(xc, bc);
    stage_b(bn, kt + 1);
    if (kt < 14) stage_x(xn2, kt + 2);
    { float* t = xc; xc = xn; xn = xn2; xn2 = t; }
    { u16* t = bc; bc = bn; bn = t; }
  }
  asm volatile("s_waitcnt vmcnt(0)" ::: "memory");
  __builtin_amdgcn_s_barrier();
  __builtin_amdgcn_sched_barrier(0);
  mfma_from(xc, bc);

  float b1r[3], g1r[3], e1r[3];
  #pragma unroll
  for (int n=0; n<3; ++n){ int c = n*16 + l15; b1r[n] = b1[c]; g1r[n] = g1[c]; e1r[n] = be1[c]; }
  #pragma unroll
  for (int r=0; r<4; ++r){
    float a0 = acc[0][r] + b1r[0];
    float a1 = acc[1][r] + b1r[1];
    float a2 = acc[2][r] + b1r[2];
    float s1 = a0+a1+a2;
    float s2 = a0*a0 + a1*a1 + a2*a2;
    #pragma unroll
    for (int m=1; m<16; m<<=1){ s1 += __shfl_xor(s1, m); s2 += __shfl_xor(s2, m); }
    float mean = s1 * (1.f/48.f);
    float var  = s2 * (1.f/48.f) - mean*mean;
    float rs = rsqrtf(var + 1e-5f);
    int row = bm*64 + w*16 + l4*4 + r;
    float* hb = hout + (size_t)row*48;
    hb[l15]      = gelu_f((a0-mean)*rs*g1r[0] + e1r[0]);
    hb[16+l15]   = gelu_f((a1-mean)*rs*g1r[1] + e1r[1]);
    hb[32+l15]   = gelu_f((a2-mean)*rs*g1r[2] + e1r[2]);
  }
}

// ---------------- K1b: ODE (2 steps, MFMA hi/lo, trunc splits) -> h64 + q2 ----------------
__global__ __launch_bounds__(256) void k_ode(
    const float* __restrict__ hin,
    const u16* __restrict__ wah, const u16* __restrict__ wbh,
    const float* __restrict__ ba, const float* __restrict__ bb,
    float* __restrict__ hout, float* __restrict__ q2b)
{
  extern __shared__ u16 sm[];
  u16* t_hi = sm;
  u16* t_lo = sm + 16384;
  u16* h_hi = sm + 32768;
  u16* h_lo = sm + 40960;
  float* hscr = (float*)sm;

  const int tid = threadIdx.x;
  const int lane = tid & 63, w = tid >> 6;
  const int l15 = lane & 15, l4 = lane >> 4;
  const int bm = blockIdx.x;

  float4 hv4[6];
  #pragma unroll
  for (int it=0; it<6; ++it){
    int q = it*256 + tid;
    int row = q/12, c4 = q - row*12;
    hv4[it] = *(const float4*)(hin + (size_t)(bm*128 + row)*48 + c4*4);
  }
  #pragma unroll
  for (int it=0; it<6; ++it){
    int q = it*256 + tid;
    int row = q/12, c4 = q - row*12;
    *(float4*)&hscr[row*48 + c4*4] = hv4[it];
    float4 v = hv4[it];
    u16 h0,l0,h1,l1,h2,l2,h3,l3;
    tsplit(v.x,h0,l0); tsplit(v.y,h1,l1); tsplit(v.z,h2,l2); tsplit(v.w,h3,l3);
    int off = row*64 + ((c4>>1) ^ (row & 7))*8 + (c4 & 1)*4;
    short4v hv = {(short)h0,(short)h1,(short)h2,(short)h3};
    short4v lv = {(short)l0,(short)l1,(short)l2,(short)l3};
    *(short4v*)&h_hi[off] = hv;
    *(short4v*)&h_lo[off] = lv;
  }
  {
    int row = tid >> 1, ch = 6 + (tid & 1);
    int off = row*64 + (ch ^ (row & 7))*8;
    uint4 z = {0u,0u,0u,0u};
    *(uint4*)&h_hi[off] = z;
    *(uint4*)&h_lo[off] = z;
  }
  __syncthreads();

  float hreg[2][3][4];
  #pragma unroll
  for (int m=0; m<2; ++m)
    #pragma unroll
    for (int n=0; n<3; ++n)
      #pragma unroll
      for (int r=0; r<4; ++r)
        hreg[m][n][r] = hscr[(w*32 + m*16 + l4*4 + r)*48 + n*16 + l15];
  __syncthreads();

  float ba_r[8], bb_r[3];
  #pragma unroll
  for (int n=0; n<8; ++n) ba_r[n] = ba[n*16 + l15];
  #pragma unroll
  for (int n=0; n<3; ++n) bb_r[n] = bb[n*16 + l15];

  for (int s=0; s<2; ++s){
    f32x4 at[2][8];
    #pragma unroll
    for (int m=0; m<2; ++m)
      #pragma unroll
      for (int n=0; n<8; ++n) at[m][n] = (f32x4){0.f,0.f,0.f,0.f};
    #pragma unroll
    for (int kq=0; kq<2; ++kq){
      short8v ah[2], al[2];
      #pragma unroll
      for (int m=0; m<2; ++m){
        int arow = w*32 + m*16 + l15;
        int ac = (kq*4 + l4) ^ (arow & 7);
        ah[m] = *(const short8v*)&h_hi[arow*64 + ac*8];
        al[m] = *(const short8v*)&h_lo[arow*64 + ac*8];
      }
      #pragma unroll
      for (int n=0; n<8; ++n){
        const u16* bp = wah + (n*16 + l15)*64 + kq*32 + l4*8;
        short8v bh = *(const short8v*)bp;
        short8v bl = *(const short8v*)(bp + 8192);
        #pragma unroll
        for (int m=0; m<2; ++m){
          at[m][n] = __builtin_amdgcn_mfma_f32_16x16x32_bf16(ah[m], bh, at[m][n], 0, 0, 0);
          at[m][n] = __builtin_amdgcn_mfma_f32_16x16x32_bf16(ah[m], bl, at[m][n], 0, 0, 0);
          at[m][n] = __builtin_amdgcn_mfma_f32_16x16x32_bf16(al[m], bh, at[m][n], 0, 0, 0);
        }
      }
    }
    #pragma unroll
    for (int m=0; m<2; ++m)
      #pragma unroll
      for (int n=0; n<8; ++n)
        #pragma unroll
        for (int r=0; r<4; ++r){
          float tv = tanh_f(at[m][n][r] + ba_r[n]);
          u16 th, tl; tsplit(tv, th, tl);
          int row = w*32 + m*16 + l4*4 + r;
          int col = n*16 + l15;
          int c = col >> 3;
          int phys = (c & 8) | ((c & 7) ^ (row & 7));
          int off = row*128 + phys*8 + (col & 7);
          t_hi[off] = th; t_lo[off] = tl;
        }
    __syncthreads();
    f32x4 ad[2][3];
    #pragma unroll
    for (int m=0; m<2; ++m)
      #pragma unroll
      for (int n=0; n<3; ++n) ad[m][n] = (f32x4){0.f,0.f,0.f,0.f};
    #pragma unroll
    for (int kq=0; kq<4; ++kq){
      short8v ah[2], al[2];
      #pragma unroll
      for (int m=0; m<2; ++m){
        int arow = w*32 + m*16 + l15;
        int c = kq*4 + l4;
        int phys = (c & 8) | ((c & 7) ^ (arow & 7));
        ah[m] = *(const short8v*)&t_hi[arow*128 + phys*8];
        al[m] = *(const short8v*)&t_lo[arow*128 + phys*8];
      }
      #pragma unroll
      for (int n=0; n<3; ++n){
        const u16* bp = wbh + (n*16 + l15)*128 + kq*32 + l4*8;
        short8v bh = *(const short8v*)bp;
        short8v bl = *(const short8v*)(bp + 6144);
        #pragma unroll
        for (int m=0; m<2; ++m){
          ad[m][n] = __builtin_amdgcn_mfma_f32_16x16x32_bf16(ah[m], bh, ad[m][n], 0, 0, 0);
          ad[m][n] = __builtin_amdgcn_mfma_f32_16x16x32_bf16(ah[m], bl, ad[m][n], 0, 0, 0);
          ad[m][n] = __builtin_amdgcn_mfma_f32_16x16x32_bf16(al[m], bh, ad[m][n], 0, 0, 0);
        }
      }
    }
    #pragma unroll
    for (int m=0; m<2; ++m)
      #pragma unroll
      for (int n=0; n<3; ++n)
        #pragma unroll
        for (int r=0; r<4; ++r)
          hreg[m][n][r] += 0.5f*(ad[m][n][r] + bb_r[n]);
    if (s == 0){
      #pragma unroll
      for (int m=0; m<2; ++m)
        #pragma unroll
        for (int n=0; n<3; ++n)
          #pragma unroll
          for (int r=0; r<4; ++r){
            u16 hh, hl2; tsplit(hreg[m][n][r], hh, hl2);
            int row = w*32 + m*16 + l4*4 + r;
            int col = n*16 + l15;
            int off = row*64 + ((col>>3) ^ (row & 7))*8 + (col & 7);
            h_hi[off] = hh; h_lo[off] = hl2;
          }
      __syncthreads();
    }
  }
  #pragma unroll
  for (int m=0; m<2; ++m){
    #pragma unroll
    for (int r=0; r<4; ++r){
      size_t row = (size_t)(bm*128 + w*32 + m*16 + l4*4 + r);
      #pragma unroll
      for (int n=0; n<3; ++n)
        hout[row*64 + n*16 + l15] = hreg[m][n][r];
      hout[row*64 + 48 + l15] = 0.f;
      float s2 = hreg[m][0][r]*hreg[m][0][r] + hreg[m][1][r]*hreg[m][1][r] + hreg[m][2][r]*hreg[m][2][r];
      #pragma unroll
      for (int msk=1; msk<16; msk<<=1) s2 += __shfl_xor(s2, msk);
      if (l15 == 0) q2b[row] = s2;
    }
  }
}

// ---------------- K2a: dist(MFMA) + top-32 select -> glist ----------------
__global__ __launch_bounds__(256, 4) void k_sel(
    const float* __restrict__ h, const float* __restrict__ q2b,
    const u16* __restrict__ posB, const float2* __restrict__ mnw,
    uint32_t* __restrict__ glist)
{
  __shared__ __align__(16) uint32_t tokKeys[2*4*528];

  const int tid = threadIdx.x;
  const int lane = tid & 63, w = tid >> 6;
  const int g = w >> 1, s = w & 1;
  const int l15 = lane & 15, l4 = lane >> 4;
  const int bm = blockIdx.x;

  const float* hrow = h + (size_t)(bm*32 + g*16 + l15)*64;
  float4 x0 = *(const float4*)(hrow + l4*8);
  float4 x1 = *(const float4*)(hrow + l4*8 + 4);
  float4 x2 = *(const float4*)(hrow + 32 + l4*8);
  float4 x3 = *(const float4*)(hrow + 32 + l4*8 + 4);
  short8v ah0, al0, ah1, al1;
  tpack8(x0, x1, ah0, al0);
  tpack8(x2, x3, ah1, al1);

  float4 q2v = *(const float4*)(q2b + bm*32 + g*16 + l4*4);
  float q2a[4] = {q2v.x, q2v.y, q2v.z, q2v.w};

  uint32_t kk[16][4];
  #pragma unroll
  for (int n=0; n<16; ++n){
    const u16* pb = posB + (size_t)(s*16 + n)*512 + lane*8;
    short8v bh0 = *(const short8v*)(pb);
    short8v bl0 = *(const short8v*)(pb + 32768);
    short8v bh1 = *(const short8v*)(pb + 16384);
    short8v bl1 = *(const short8v*)(pb + 49152);
    f32x4 acc = (f32x4){0.f,0.f,0.f,0.f};
    acc = __builtin_amdgcn_mfma_f32_16x16x32_bf16(ah0, bh0, acc, 0, 0, 0);
    acc = __builtin_amdgcn_mfma_f32_16x16x32_bf16(ah0, bl0, acc, 0, 0, 0);
    acc = __builtin_amdgcn_mfma_f32_16x16x32_bf16(al0, bh0, acc, 0, 0, 0);
    acc = __builtin_amdgcn_mfma_f32_16x16x32_bf16(ah1, bh1, acc, 0, 0, 0);
    acc = __builtin_amdgcn_mfma_f32_16x16x32_bf16(ah1, bl1, acc, 0, 0, 0);
    acc = __builtin_amdgcn_mfma_f32_16x16x32_bf16(al1, bh1, acc, 0, 0, 0);
    const int slot = s*256 + n*16 + l15;
    float2 mw = mnw[slot];
    #pragma unroll
    for (int r=0; r<4; ++r){
      float dd = fmaxf(q2a[r] + mw.x - 2.f*acc[r], 0.f) * mw.y;
      kk[n][r] = (__float_as_uint(dd) & 0xFFFFFE00u) | (uint32_t)slot;
    }
  }

  const int gbase = g*2112;
  const unsigned long long ltmask = (lane == 63) ? 0x7FFFFFFFFFFFFFFFull : ((1ull << lane) - 1ull);
  #pragma unroll
  for (int r=0; r<4; ++r){
    __syncthreads();
    #pragma unroll
    for (int n=0; n<16; ++n)
      tokKeys[gbase + l4*528 + s*256 + n*16 + l15] = kk[n][r];
    __syncthreads();
    uint32_t key8[2][8];
    #pragma unroll
    for (int j=0; j<2; ++j){
      *(uint4*)&key8[j][0] = *(const uint4*)&tokKeys[gbase + (s*2+j)*528 + lane*8];
      *(uint4*)&key8[j][4] = *(const uint4*)&tokKeys[gbase + (s*2+j)*528 + lane*8 + 4];
    }
    uint32_t p[2] = {0u,0u};
    for (int b=30; b>=0; --b){
      #pragma unroll
      for (int j=0; j<2; ++j){
        uint32_t c = p[j] | (1u<<b);
        int cnt = 0;
        #pragma unroll
        for (int i=0; i<8; ++i) cnt += (int)__popcll(__ballot(key8[j][i] < c));
        if (cnt <= 31) p[j] = c;
      }
    }
    #pragma unroll
    for (int j=0; j<2; ++j){
      size_t tok = (size_t)bm*32 + g*16 + (s*2+j)*4 + r;
      int base = 0;
      #pragma unroll
      for (int i=0; i<8; ++i){
        unsigned long long bal = __ballot(key8[j][i] <= p[j]);
        if (key8[j][i] <= p[j]){
          int idx = base + (int)__popcll(bal & ltmask);
          glist[tok*32 + idx] = key8[j][i];
        }
        base += (int)__popcll(bal);
      }
    }
  }
}

// ---------------- K2b: softmax + gather-accumulate (wave per token) ----------------
__global__ __launch_bounds__(256) void k_attend(
    const uint32_t* __restrict__ glist, const u16* __restrict__ memb,
    u16* __restrict__ att)
{
  const int lane = threadIdx.x & 63, w = threadIdx.x >> 6;
  const size_t tok = (size_t)blockIdx.x*4 + w;
  uint32_t lk[32];
  const uint4* lp = (const uint4*)(glist + tok*32);
  #pragma unroll
  for (int q=0; q<8; ++q) *(uint4*)&lk[q*4] = lp[q];
  uint32_t km = lk[0];
  #pragma unroll
  for (int i=1; i<32; ++i) km = min(km, lk[i]);
  const float dminf = __uint_as_float(km & 0xFFFFFE00u);

  float den = 0.f, a0=0.f, a1=0.f, a2=0.f, a3=0.f;
  #pragma unroll
  for (int i=0; i<32; ++i){
    float dk = __uint_as_float(lk[i] & 0xFFFFFE00u);
    int slot = (int)(lk[i] & 511u);
    float wg = __expf(dminf - dk);
    den += wg;
    uint2 mv = ((const uint2*)(memb + (size_t)slot*256))[lane];
    a0 += wg*bf2f((u16)(mv.x & 0xFFFFu));
    a1 += wg*bf2f((u16)(mv.x >> 16));
    a2 += wg*bf2f((u16)(mv.y & 0xFFFFu));
    a3 += wg*bf2f((u16)(mv.y >> 16));
  }
  float inv = 1.f/den;
  uint32_t o0 = (uint32_t)f2bf(a0*inv) | ((uint32_t)f2bf(a1*inv) << 16);
  uint32_t o1 = (uint32_t)f2bf(a2*inv) | ((uint32_t)f2bf(a3*inv) << 16);
  ((uint2*)(att + tok*256))[lane] = make_uint2(o0, o1);
}

// ---------------- K4+K5 fused: att @ wo + bo -> LN(1024) -> GELU(tanh) -> out fp32 ----------------
// 64 tokens x 1024 cols, 1024 threads (16 waves). NEW wave tiling: each wave computes
// 64 rows x 64 cols (4 m-tiles x 4 n-tiles) instead of 16 rows x 256 cols.
// B-fragment reuse goes 1x -> 4x: woB L2 traffic drops 1 GB -> 256 MB, and each B load
// feeds 4 independent MFMAs (ILP). woB layout unchanged: fragment (kt, ct) at (kt*64+ct)*512.
// LN(1024) partials now combine across 16 waves via stride-65-padded LDS (<=2-way bank alias).
__global__ __launch_bounds__(1024, 4) void k_out(
    const u16* __restrict__ A, const u16* __restrict__ woB, const float* __restrict__ bo,
    const float* __restrict__ go, const float* __restrict__ beo, float* __restrict__ out)
{
  __shared__ u16 Asl[64*256];          // 32 KB swizzled A copy
  __shared__ float red1[16*65];        // per-wave LN partial sums (stride-65 pad)
  __shared__ float red2[16*65];        // per-wave LN partial sum-of-squares

  const int tid = threadIdx.x;
  const int lane = tid & 63, w = tid >> 6;   // w = column-group: cols [w*64, w*64+64)
  const int l15 = lane & 15, l4 = lane >> 4;
  const int bm = blockIdx.x;

  #pragma unroll
  for (int j=0; j<2; ++j){
    int idx = j*1024 + tid;
    int row = idx >> 5, ch = idx & 31;
    int gc = (ch & 24) | ((ch & 7) ^ (row & 7));
    uint4 v = *(const uint4*)(A + (size_t)(bm*64 + row)*256 + gc*8);
    *(uint4*)&Asl[row*256 + ch*8] = v;
  }
  __syncthreads();

  f32x4 acc[4][4];   // [m-tile][n-tile]
  #pragma unroll
  for (int m=0; m<4; ++m)
    #pragma unroll
    for (int n=0; n<4; ++n) acc[m][n] = (f32x4){0.f,0.f,0.f,0.f};

  #pragma unroll
  for (int kt=0; kt<8; ++kt){
    const int c = kt*4 + l4;
    short8v af[4];
    #pragma unroll
    for (int m=0; m<4; ++m){
      int arow = m*16 + l15;
      int aphys = (c & 24) | ((c & 7) ^ (arow & 7));
      af[m] = *(const short8v*)&Asl[arow*256 + aphys*8];
    }
    // woB fragment-linear: fragment (kt, ct) at (kt*64 + ct)*512; this wave uses ct = w*4..w*4+3
    const u16* bbase = woB + ((size_t)kt*64 + w*4)*512 + lane*8;
    #pragma unroll
    for (int n=0; n<4; ++n){
      short8v bf = *(const short8v*)(bbase + n*512);
      #pragma unroll
      for (int m=0; m<4; ++m)
        acc[m][n] = __builtin_amdgcn_mfma_f32_16x16x32_bf16(af[m], bf, acc[m][n], 0, 0, 0);
    }
  }

  float bor[4];
  #pragma unroll
  for (int n=0; n<4; ++n) bor[n] = bo[w*64 + n*16 + l15];

  // per-(m,r) row partials over this wave's 64 columns
  float s1[4][4], s2[4][4];
  #pragma unroll
  for (int m=0; m<4; ++m)
    #pragma unroll
    for (int r=0; r<4; ++r){ s1[m][r] = 0.f; s2[m][r] = 0.f; }
  #pragma unroll
  for (int m=0; m<4; ++m)
    #pragma unroll
    for (int n=0; n<4; ++n)
      #pragma unroll
      for (int r=0; r<4; ++r){
        float v = acc[m][n][r] + bor[n];
        acc[m][n][r] = v;
        s1[m][r] += v; s2[m][r] += v*v;
      }
  #pragma unroll
  for (int m=0; m<4; ++m)
    #pragma unroll
    for (int r=0; r<4; ++r){
      #pragma unroll
      for (int msk=1; msk<16; msk<<=1){
        s1[m][r] += __shfl_xor(s1[m][r], msk);
        s2[m][r] += __shfl_xor(s2[m][r], msk);
      }
    }
  if (l15 == 0){
    #pragma unroll
    for (int m=0; m<4; ++m)
      #pragma unroll
      for (int r=0; r<4; ++r){
        int t = m*16 + l4*4 + r;
        red1[w*65 + t] = s1[m][r];
        red2[w*65 + t] = s2[m][r];
      }
  }
  __syncthreads();

  // combine 16 wave-partials per row: lane l15 holds wave-l15's partial, shfl-reduce
  float mean[4][4], rs[4][4];
  #pragma unroll
  for (int m=0; m<4; ++m)
    #pragma unroll
    for (int r=0; r<4; ++r){
      int t = m*16 + l4*4 + r;
      float a1 = red1[l15*65 + t];
      float a2 = red2[l15*65 + t];
      #pragma unroll
      for (int msk=1; msk<16; msk<<=1){
        a1 += __shfl_xor(a1, msk);
        a2 += __shfl_xor(a2, msk);
      }
      float mu = a1 * (1.f/1024.f);
      float var = a2 * (1.f/1024.f) - mu*mu;
      mean[m][r] = mu;
      rs[m][r] = rsqrtf(var + 1e-5f);
    }

  #pragma unroll
  for (int n=0; n<4; ++n){
    int col = w*64 + n*16 + l15;
    float g = go[col], e = beo[col];
    #pragma unroll
    for (int m=0; m<4; ++m)
      #pragma unroll
      for (int r=0; r<4; ++r){
        size_t row = (size_t)bm*64 + m*16 + l4*4 + r;
        out[row*1024 + col] = gelu_t((acc[m][n][r] - mean[m][r])*rs[m][r]*g + e);
      }
  }
}

extern "C" void kernel_launch(void* const* d_in, const int* in_sizes, int n_in,
                              void* d_out, int out_size, void* d_ws, size_t ws_size,
                              hipStream_t stream) {
  const float* x    = (const float*)d_in[0];
  const float* w1   = (const float*)d_in[1];
  const float* b1   = (const float*)d_in[2];
  const float* g1   = (const float*)d_in[3];
  const float* be1  = (const float*)d_in[4];
  const float* wa   = (const float*)d_in[5];
  const float* ba   = (const float*)d_in[6];
  const float* wb   = (const float*)d_in[7];
  const float* bb   = (const float*)d_in[8];
  const float* mem  = (const float*)d_in[9];
  const float* pos  = (const float*)d_in[10];
  const float* curv = (const float*)d_in[11];
  const float* alpha= (const float*)d_in[12];
  const float* wo   = (const float*)d_in[13];
  const float* bo   = (const float*)d_in[14];
  const float* go   = (const float*)d_in[15];
  const float* beo  = (const float*)d_in[16];
  float* out = (float*)d_out;

  char* ws = (char*)d_ws;
  size_t o = 0;
  auto take = [&](size_t b) -> char* { char* p = ws + o; o += (b + 255) & ~(size_t)255; return p; };
  char*  regA   = take(67108864);
  float* hbuf48 = (float*)regA;
  float* hbuf64 = (float*)(regA + 6291456);
  float* q2b    = (float*)(regA + 6291456 + 8388608);
  u16*   att    = (u16*)take(16777216);
  u16*   w1s    = (u16*)take(196608);
  u16*   wah    = (u16*)take(32768);
  u16*   wbh    = (u16*)take(24576);
  float2* mnw   = (float2*)take(4096);
  u16*   memb   = (u16*)take(262144);
  u16*   woB    = (u16*)take(524288);
  u16*   posB   = (u16*)take(131072);
  uint32_t* glist = (uint32_t*)take(4194304);

  hipFuncSetAttribute((const void*)k_ode, hipFuncAttributeMaxDynamicSharedMemorySize, 98304);
  hipFuncSetAttribute((const void*)k_proj, hipFuncAttributeMaxDynamicSharedMemorySize, 73728);

  k_prep<<<1914, 256, 0, stream>>>(w1, wa, wb, pos, curv, mem, wo, alpha,
                                   w1s, wah, wbh, mnw, memb, woB, posB);
  k_proj<<<512, 256, 73728, stream>>>(x, w1s, b1, g1, be1, hbuf48);
  k_ode<<<256, 256, 98304, stream>>>(hbuf48, wah, wbh, ba, bb, hbuf64, q2b);
  k_sel<<<1024, 256, 0, stream>>>(hbuf64, q2b, posB, mnw, glist);
  k_attend<<<8192, 256, 0, stream>>>(glist, memb, att);
  k_out<<<512, 1024, 0, stream>>>(att, woB, bo, go, beo, out);
  (void)in_sizes; (void)n_in; (void)out_size; (void)ws_size;
}

// Round 2
// 232.929 us; speedup vs baseline: 1.1444x; 1.1444x over previous
//
#include <hip/hip_runtime.h>
#include <stdint.h>

typedef unsigned short u16;
typedef __attribute__((ext_vector_type(4))) short short4v;
typedef __attribute__((ext_vector_type(8))) short short8v;
typedef __attribute__((ext_vector_type(4))) float f32x4;
typedef __attribute__((address_space(1))) void gv;
typedef __attribute__((address_space(3))) void lv;

#define NTOK 32768

__device__ __forceinline__ float bf2f(u16 u){ return __uint_as_float(((uint32_t)u)<<16); }
__device__ __forceinline__ u16 f2bf(float f){
  uint32_t u = __float_as_uint(f);
  u += 0x7FFFu + ((u>>16)&1u);
  return (u16)(u>>16);
}
// RNE split (prep only)
__device__ __forceinline__ void hilo(float v, u16& h, u16& l){
  h = f2bf(v);
  l = f2bf(v - bf2f(h));
}
// truncating split (hot paths)
__device__ __forceinline__ void tsplit(float v, u16& h, u16& l){
  uint32_t b = __float_as_uint(v);
  h = (u16)(b >> 16);
  float lf = v - __uint_as_float(b & 0xFFFF0000u);
  l = (u16)(__float_as_uint(lf) >> 16);
}
__device__ __forceinline__ void tpack8(float4 a, float4 b, short8v& hi, short8v& lo){
  float v[8] = {a.x,a.y,a.z,a.w,b.x,b.y,b.z,b.w};
  #pragma unroll
  for (int i=0;i<8;++i){ u16 h,l; tsplit(v[i],h,l); hi[i]=(short)h; lo[i]=(short)l; }
}
__device__ __forceinline__ float gelu_f(float v){ return 0.5f*v*(1.0f + erff(v*0.70710678118654752440f)); }
// tanh-approx GELU (output kernel only): max abs dev from exact ~3e-4, ~8 VALU ops
__device__ __forceinline__ float gelu_t(float x){
  float u = 0.7978845608028654f*(x + 0.044715f*x*x*x);
  float t = 1.0f - 2.0f/(__expf(2.0f*u) + 1.0f);
  return 0.5f*x*(1.0f + t);
}
__device__ __forceinline__ float tanh_f(float x){ return 1.0f - 2.0f/(__expf(2.0f*x)+1.0f); }

// ---------------- K0: prep ----------------
// woB: fragment-linear B of wo^T: i = (((kt*4+cp)*16+n)*64 + ln)*8 + e
__global__ __launch_bounds__(256) void k_prep(
    const float* __restrict__ w1, const float* __restrict__ wa, const float* __restrict__ wb,
    const float* __restrict__ pos, const float* __restrict__ curv,
    const float* __restrict__ mem, const float* __restrict__ wo,
    const float* __restrict__ alpha,
    u16* __restrict__ w1s, u16* __restrict__ wah, u16* __restrict__ wbh,
    float2* __restrict__ mnw,
    u16* __restrict__ memb, u16* __restrict__ woB, u16* __restrict__ posB)
{
  int i = blockIdx.x*256 + threadIdx.x;
  if (i < 49152){ int n = i>>10, k = i&1023; u16 h,l; hilo(w1[k*48+n], h, l);
                  w1s[i] = h; w1s[49152+i] = l; return; }
  i -= 49152;
  if (i < 8192){ int u = i>>6, d = i&63; float v = (d<48) ? wa[d*128+u] : 0.f;
                 u16 h,l; hilo(v,h,l); wah[i] = h; wah[8192+i] = l; return; }
  i -= 8192;
  if (i < 6144){ int n = i>>7, u = i&127; u16 h,l; hilo(wb[u*48+n], h, l);
                 wbh[i] = h; wbh[6144+i] = l; return; }
  i -= 6144;
  if (i < 512){
    float s = 0.f;
    #pragma unroll
    for (int d=0; d<48; ++d){ float v = pos[i*48+d]; s += v*v; }
    float c2 = 0.f;
    #pragma unroll
    for (int d=0; d<16; ++d){ float v = curv[i*16+d]; c2 += v*v; }
    mnw[i] = make_float2(s, expf(-alpha[0]*sqrtf(c2)));
    return;
  }
  i -= 512;
  if (i < 131072){ memb[i] = f2bf(mem[i]); return; }
  i -= 131072;
  if (i < 262144){
    int e = i & 7, ln = (i>>3)&63, n = (i>>9)&15, cpq = (i>>13)&3, kt = i>>15;
    int col = cpq*256 + n*16 + (ln & 15);
    int k   = kt*32 + (ln >> 4)*8 + e;
    woB[i] = f2bf(wo[k*1024 + col]);
    return;
  }
  i -= 262144;
  if (i < 32768){
    int e = i & 7, ln = (i>>3)&63, n = (i>>9)&31, ks = i>>14;
    int slot = n*16 + (ln&15);
    int d = ks*32 + (ln>>4)*8 + e;
    float v = (d < 48) ? pos[slot*48 + d] : 0.f;
    u16 h,l; hilo(v,h,l);
    posB[i] = h; posB[32768+i] = l;
  }
}

// ---------------- K1: x@w1 via global_load_lds pipeline + LN(48) + GELU -> h48 ----------------
__global__ __launch_bounds__(256, 2) void k_proj(
    const float* __restrict__ x, const u16* __restrict__ w1s,
    const float* __restrict__ b1, const float* __restrict__ g1, const float* __restrict__ be1,
    float* __restrict__ hout)
{
  extern __shared__ char dynp[];
  float* xsl = (float*)dynp;                 // 3 * 4096 floats
  u16*   bsl = (u16*)(dynp + 49152);         // 2 * 6144 u16

  const int tid = threadIdx.x;
  const int lane = tid & 63, w = tid >> 6;
  const int l15 = lane & 15, l4 = lane >> 4;
  const int bm = blockIdx.x;
  const int arow = w*16 + l15;

  f32x4 acc[3];
  #pragma unroll
  for (int n=0; n<3; ++n) acc[n] = (f32x4){0.f,0.f,0.f,0.f};

  auto stage_x = [&](float* dst, int kt){
    #pragma unroll
    for (int j=0; j<4; ++j){
      int idx = (j*4 + w)*64 + lane;
      int row = idx >> 4, q = idx & 15;
      int chunk = q >> 1, half = q & 1;
      const float* src = x + (size_t)(bm*64 + row)*1024 + kt*64 + ((chunk ^ (row & 7))*8 + half*4);
      __builtin_amdgcn_global_load_lds((gv*)src, (lv*)(dst + (j*4 + w)*256), 16, 0, 0);
    }
  };
  auto stage_b = [&](u16* dst, int kt){
    #pragma unroll
    for (int j=0; j<3; ++j){
      int idx = (j*4 + w)*64 + lane;
      int hl = (idx >= 384) ? 1 : 0;
      int rr = idx - hl*384;
      int row = rr >> 3, ch = rr & 7;
      const u16* src = w1s + hl*49152 + (size_t)row*1024 + kt*64 + ((ch ^ (row & 7))*8);
      __builtin_amdgcn_global_load_lds((gv*)src, (lv*)(dst + (j*4 + w)*512), 16, 0, 0);
    }
  };
  auto mfma_from = [&](const float* xb, const u16* bb){
    #pragma unroll
    for (int kq=0; kq<2; ++kq){
      int chunk = kq*4 + l4;
      int phys = chunk ^ (arow & 7);
      const float* xa = xb + arow*64 + phys*8;
      float4 a0 = *(const float4*)xa;
      float4 a1 = *(const float4*)(xa + 4);
      short8v ah, al; tpack8(a0, a1, ah, al);
      #pragma unroll
      for (int n=0; n<3; ++n){
        int brow = n*16 + l15;
        int bcx = chunk ^ (brow & 7);
        short8v bh = *(const short8v*)(bb + brow*64 + bcx*8);
        short8v bl = *(const short8v*)(bb + 3072 + brow*64 + bcx*8);
        acc[n] = __builtin_amdgcn_mfma_f32_16x16x32_bf16(ah, bh, acc[n], 0, 0, 0);
        acc[n] = __builtin_amdgcn_mfma_f32_16x16x32_bf16(ah, bl, acc[n], 0, 0, 0);
        acc[n] = __builtin_amdgcn_mfma_f32_16x16x32_bf16(al, bh, acc[n], 0, 0, 0);
      }
    }
  };

  float* x0 = xsl;         float* x1 = xsl + 4096;  float* x2 = xsl + 8192;
  u16*   b0 = bsl;         u16*   b1b = bsl + 6144;

  stage_b(b0, 0);
  stage_x(x0, 0);
  stage_x(x1, 1);

  float* xc = x0; float* xn = x1; float* xn2 = x2;
  u16* bc = b0;  u16* bn = b1b;

  for (int kt = 0; kt < 15; ++kt){
    asm volatile("s_waitcnt vmcnt(4)" ::: "memory");
    __builtin_amdgcn_s_barrier();
    __builtin_amdgcn_sched_barrier(0);
    mfma_from(xc, bc);
    stage_b(bn, kt + 1);
    if (kt < 14) stage_x(xn2, kt + 2);
    { float* t = xc; xc = xn; xn = xn2; xn2 = t; }
    { u16* t = bc; bc = bn; bn = t; }
  }
  asm volatile("s_waitcnt vmcnt(0)" ::: "memory");
  __builtin_amdgcn_s_barrier();
  __builtin_amdgcn_sched_barrier(0);
  mfma_from(xc, bc);

  float b1r[3], g1r[3], e1r[3];
  #pragma unroll
  for (int n=0; n<3; ++n){ int c = n*16 + l15; b1r[n] = b1[c]; g1r[n] = g1[c]; e1r[n] = be1[c]; }
  #pragma unroll
  for (int r=0; r<4; ++r){
    float a0 = acc[0][r] + b1r[0];
    float a1 = acc[1][r] + b1r[1];
    float a2 = acc[2][r] + b1r[2];
    float s1 = a0+a1+a2;
    float s2 = a0*a0 + a1*a1 + a2*a2;
    #pragma unroll
    for (int m=1; m<16; m<<=1){ s1 += __shfl_xor(s1, m); s2 += __shfl_xor(s2, m); }
    float mean = s1 * (1.f/48.f);
    float var  = s2 * (1.f/48.f) - mean*mean;
    float rs = rsqrtf(var + 1e-5f);
    int row = bm*64 + w*16 + l4*4 + r;
    float* hb = hout + (size_t)row*48;
    hb[l15]      = gelu_f((a0-mean)*rs*g1r[0] + e1r[0]);
    hb[16+l15]   = gelu_f((a1-mean)*rs*g1r[1] + e1r[1]);
    hb[32+l15]   = gelu_f((a2-mean)*rs*g1r[2] + e1r[2]);
  }
}

// ---------------- K1b: ODE (2 steps, MFMA hi/lo, trunc splits) -> h64 + q2 ----------------
__global__ __launch_bounds__(256) void k_ode(
    const float* __restrict__ hin,
    const u16* __restrict__ wah, const u16* __restrict__ wbh,
    const float* __restrict__ ba, const float* __restrict__ bb,
    float* __restrict__ hout, float* __restrict__ q2b)
{
  extern __shared__ u16 sm[];
  u16* t_hi = sm;
  u16* t_lo = sm + 16384;
  u16* h_hi = sm + 32768;
  u16* h_lo = sm + 40960;
  float* hscr = (float*)sm;

  const int tid = threadIdx.x;
  const int lane = tid & 63, w = tid >> 6;
  const int l15 = lane & 15, l4 = lane >> 4;
  const int bm = blockIdx.x;

  float4 hv4[6];
  #pragma unroll
  for (int it=0; it<6; ++it){
    int q = it*256 + tid;
    int row = q/12, c4 = q - row*12;
    hv4[it] = *(const float4*)(hin + (size_t)(bm*128 + row)*48 + c4*4);
  }
  #pragma unroll
  for (int it=0; it<6; ++it){
    int q = it*256 + tid;
    int row = q/12, c4 = q - row*12;
    *(float4*)&hscr[row*48 + c4*4] = hv4[it];
    float4 v = hv4[it];
    u16 h0,l0,h1,l1,h2,l2,h3,l3;
    tsplit(v.x,h0,l0); tsplit(v.y,h1,l1); tsplit(v.z,h2,l2); tsplit(v.w,h3,l3);
    int off = row*64 + ((c4>>1) ^ (row & 7))*8 + (c4 & 1)*4;
    short4v hv = {(short)h0,(short)h1,(short)h2,(short)h3};
    short4v lv = {(short)l0,(short)l1,(short)l2,(short)l3};
    *(short4v*)&h_hi[off] = hv;
    *(short4v*)&h_lo[off] = lv;
  }
  {
    int row = tid >> 1, ch = 6 + (tid & 1);
    int off = row*64 + (ch ^ (row & 7))*8;
    uint4 z = {0u,0u,0u,0u};
    *(uint4*)&h_hi[off] = z;
    *(uint4*)&h_lo[off] = z;
  }
  __syncthreads();

  float hreg[2][3][4];
  #pragma unroll
  for (int m=0; m<2; ++m)
    #pragma unroll
    for (int n=0; n<3; ++n)
      #pragma unroll
      for (int r=0; r<4; ++r)
        hreg[m][n][r] = hscr[(w*32 + m*16 + l4*4 + r)*48 + n*16 + l15];
  __syncthreads();

  float ba_r[8], bb_r[3];
  #pragma unroll
  for (int n=0; n<8; ++n) ba_r[n] = ba[n*16 + l15];
  #pragma unroll
  for (int n=0; n<3; ++n) bb_r[n] = bb[n*16 + l15];

  for (int s=0; s<2; ++s){
    f32x4 at[2][8];
    #pragma unroll
    for (int m=0; m<2; ++m)
      #pragma unroll
      for (int n=0; n<8; ++n) at[m][n] = (f32x4){0.f,0.f,0.f,0.f};
    #pragma unroll
    for (int kq=0; kq<2; ++kq){
      short8v ah[2], al[2];
      #pragma unroll
      for (int m=0; m<2; ++m){
        int arow = w*32 + m*16 + l15;
        int ac = (kq*4 + l4) ^ (arow & 7);
        ah[m] = *(const short8v*)&h_hi[arow*64 + ac*8];
        al[m] = *(const short8v*)&h_lo[arow*64 + ac*8];
      }
      #pragma unroll
      for (int n=0; n<8; ++n){
        const u16* bp = wah + (n*16 + l15)*64 + kq*32 + l4*8;
        short8v bh = *(const short8v*)bp;
        short8v bl = *(const short8v*)(bp + 8192);
        #pragma unroll
        for (int m=0; m<2; ++m){
          at[m][n] = __builtin_amdgcn_mfma_f32_16x16x32_bf16(ah[m], bh, at[m][n], 0, 0, 0);
          at[m][n] = __builtin_amdgcn_mfma_f32_16x16x32_bf16(ah[m], bl, at[m][n], 0, 0, 0);
          at[m][n] = __builtin_amdgcn_mfma_f32_16x16x32_bf16(al[m], bh, at[m][n], 0, 0, 0);
        }
      }
    }
    #pragma unroll
    for (int m=0; m<2; ++m)
      #pragma unroll
      for (int n=0; n<8; ++n)
        #pragma unroll
        for (int r=0; r<4; ++r){
          float tv = tanh_f(at[m][n][r] + ba_r[n]);
          u16 th, tl; tsplit(tv, th, tl);
          int row = w*32 + m*16 + l4*4 + r;
          int col = n*16 + l15;
          int c = col >> 3;
          int phys = (c & 8) | ((c & 7) ^ (row & 7));
          int off = row*128 + phys*8 + (col & 7);
          t_hi[off] = th; t_lo[off] = tl;
        }
    __syncthreads();
    f32x4 ad[2][3];
    #pragma unroll
    for (int m=0; m<2; ++m)
      #pragma unroll
      for (int n=0; n<3; ++n) ad[m][n] = (f32x4){0.f,0.f,0.f,0.f};
    #pragma unroll
    for (int kq=0; kq<4; ++kq){
      short8v ah[2], al[2];
      #pragma unroll
      for (int m=0; m<2; ++m){
        int arow = w*32 + m*16 + l15;
        int c = kq*4 + l4;
        int phys = (c & 8) | ((c & 7) ^ (arow & 7));
        ah[m] = *(const short8v*)&t_hi[arow*128 + phys*8];
        al[m] = *(const short8v*)&t_lo[arow*128 + phys*8];
      }
      #pragma unroll
      for (int n=0; n<3; ++n){
        const u16* bp = wbh + (n*16 + l15)*128 + kq*32 + l4*8;
        short8v bh = *(const short8v*)bp;
        short8v bl = *(const short8v*)(bp + 6144);
        #pragma unroll
        for (int m=0; m<2; ++m){
          ad[m][n] = __builtin_amdgcn_mfma_f32_16x16x32_bf16(ah[m], bh, ad[m][n], 0, 0, 0);
          ad[m][n] = __builtin_amdgcn_mfma_f32_16x16x32_bf16(ah[m], bl, ad[m][n], 0, 0, 0);
          ad[m][n] = __builtin_amdgcn_mfma_f32_16x16x32_bf16(al[m], bh, ad[m][n], 0, 0, 0);
        }
      }
    }
    #pragma unroll
    for (int m=0; m<2; ++m)
      #pragma unroll
      for (int n=0; n<3; ++n)
        #pragma unroll
        for (int r=0; r<4; ++r)
          hreg[m][n][r] += 0.5f*(ad[m][n][r] + bb_r[n]);
    if (s == 0){
      #pragma unroll
      for (int m=0; m<2; ++m)
        #pragma unroll
        for (int n=0; n<3; ++n)
          #pragma unroll
          for (int r=0; r<4; ++r){
            u16 hh, hl2; tsplit(hreg[m][n][r], hh, hl2);
            int row = w*32 + m*16 + l4*4 + r;
            int col = n*16 + l15;
            int off = row*64 + ((col>>3) ^ (row & 7))*8 + (col & 7);
            h_hi[off] = hh; h_lo[off] = hl2;
          }
      __syncthreads();
    }
  }
  #pragma unroll
  for (int m=0; m<2; ++m){
    #pragma unroll
    for (int r=0; r<4; ++r){
      size_t row = (size_t)(bm*128 + w*32 + m*16 + l4*4 + r);
      #pragma unroll
      for (int n=0; n<3; ++n)
        hout[row*64 + n*16 + l15] = hreg[m][n][r];
      hout[row*64 + 48 + l15] = 0.f;
      float s2 = hreg[m][0][r]*hreg[m][0][r] + hreg[m][1][r]*hreg[m][1][r] + hreg[m][2][r]*hreg[m][2][r];
      #pragma unroll
      for (int msk=1; msk<16; msk<<=1) s2 += __shfl_xor(s2, msk);
      if (l15 == 0) q2b[row] = s2;
    }
  }
}

// ---------------- K2a: dist(MFMA) + top-32 select -> glist ----------------
__global__ __launch_bounds__(256, 4) void k_sel(
    const float* __restrict__ h, const float* __restrict__ q2b,
    const u16* __restrict__ posB, const float2* __restrict__ mnw,
    uint32_t* __restrict__ glist)
{
  __shared__ __align__(16) uint32_t tokKeys[2*4*528];

  const int tid = threadIdx.x;
  const int lane = tid & 63, w = tid >> 6;
  const int g = w >> 1, s = w & 1;
  const int l15 = lane & 15, l4 = lane >> 4;
  const int bm = blockIdx.x;

  const float* hrow = h + (size_t)(bm*32 + g*16 + l15)*64;
  float4 x0 = *(const float4*)(hrow + l4*8);
  float4 x1 = *(const float4*)(hrow + l4*8 + 4);
  float4 x2 = *(const float4*)(hrow + 32 + l4*8);
  float4 x3 = *(const float4*)(hrow + 32 + l4*8 + 4);
  short8v ah0, al0, ah1, al1;
  tpack8(x0, x1, ah0, al0);
  tpack8(x2, x3, ah1, al1);

  float4 q2v = *(const float4*)(q2b + bm*32 + g*16 + l4*4);
  float q2a[4] = {q2v.x, q2v.y, q2v.z, q2v.w};

  uint32_t kk[16][4];
  #pragma unroll
  for (int n=0; n<16; ++n){
    const u16* pb = posB + (size_t)(s*16 + n)*512 + lane*8;
    short8v bh0 = *(const short8v*)(pb);
    short8v bl0 = *(const short8v*)(pb + 32768);
    short8v bh1 = *(const short8v*)(pb + 16384);
    short8v bl1 = *(const short8v*)(pb + 49152);
    f32x4 acc = (f32x4){0.f,0.f,0.f,0.f};
    acc = __builtin_amdgcn_mfma_f32_16x16x32_bf16(ah0, bh0, acc, 0, 0, 0);
    acc = __builtin_amdgcn_mfma_f32_16x16x32_bf16(ah0, bl0, acc, 0, 0, 0);
    acc = __builtin_amdgcn_mfma_f32_16x16x32_bf16(al0, bh0, acc, 0, 0, 0);
    acc = __builtin_amdgcn_mfma_f32_16x16x32_bf16(ah1, bh1, acc, 0, 0, 0);
    acc = __builtin_amdgcn_mfma_f32_16x16x32_bf16(ah1, bl1, acc, 0, 0, 0);
    acc = __builtin_amdgcn_mfma_f32_16x16x32_bf16(al1, bh1, acc, 0, 0, 0);
    const int slot = s*256 + n*16 + l15;
    float2 mw = mnw[slot];
    #pragma unroll
    for (int r=0; r<4; ++r){
      float dd = fmaxf(q2a[r] + mw.x - 2.f*acc[r], 0.f) * mw.y;
      kk[n][r] = (__float_as_uint(dd) & 0xFFFFFE00u) | (uint32_t)slot;
    }
  }

  const int gbase = g*2112;
  const unsigned long long ltmask = (lane == 63) ? 0x7FFFFFFFFFFFFFFFull : ((1ull << lane) - 1ull);
  #pragma unroll
  for (int r=0; r<4; ++r){
    __syncthreads();
    #pragma unroll
    for (int n=0; n<16; ++n)
      tokKeys[gbase + l4*528 + s*256 + n*16 + l15] = kk[n][r];
    __syncthreads();
    uint32_t key8[2][8];
    #pragma unroll
    for (int j=0; j<2; ++j){
      *(uint4*)&key8[j][0] = *(const uint4*)&tokKeys[gbase + (s*2+j)*528 + lane*8];
      *(uint4*)&key8[j][4] = *(const uint4*)&tokKeys[gbase + (s*2+j)*528 + lane*8 + 4];
    }
    uint32_t p[2] = {0u,0u};
    for (int b=30; b>=0; --b){
      #pragma unroll
      for (int j=0; j<2; ++j){
        uint32_t c = p[j] | (1u<<b);
        int cnt = 0;
        #pragma unroll
        for (int i=0; i<8; ++i) cnt += (int)__popcll(__ballot(key8[j][i] < c));
        if (cnt <= 31) p[j] = c;
      }
    }
    #pragma unroll
    for (int j=0; j<2; ++j){
      size_t tok = (size_t)bm*32 + g*16 + (s*2+j)*4 + r;
      int base = 0;
      #pragma unroll
      for (int i=0; i<8; ++i){
        unsigned long long bal = __ballot(key8[j][i] <= p[j]);
        if (key8[j][i] <= p[j]){
          int idx = base + (int)__popcll(bal & ltmask);
          glist[tok*32 + idx] = key8[j][i];
        }
        base += (int)__popcll(bal);
      }
    }
  }
}

// ---------------- K2b: softmax + gather-accumulate (wave per token) ----------------
__global__ __launch_bounds__(256) void k_attend(
    const uint32_t* __restrict__ glist, const u16* __restrict__ memb,
    u16* __restrict__ att)
{
  const int lane = threadIdx.x & 63, w = threadIdx.x >> 6;
  const size_t tok = (size_t)blockIdx.x*4 + w;
  uint32_t lk[32];
  const uint4* lp = (const uint4*)(glist + tok*32);
  #pragma unroll
  for (int q=0; q<8; ++q) *(uint4*)&lk[q*4] = lp[q];
  uint32_t km = lk[0];
  #pragma unroll
  for (int i=1; i<32; ++i) km = min(km, lk[i]);
  const float dminf = __uint_as_float(km & 0xFFFFFE00u);

  float den = 0.f, a0=0.f, a1=0.f, a2=0.f, a3=0.f;
  #pragma unroll
  for (int i=0; i<32; ++i){
    float dk = __uint_as_float(lk[i] & 0xFFFFFE00u);
    int slot = (int)(lk[i] & 511u);
    float wg = __expf(dminf - dk);
    den += wg;
    uint2 mv = ((const uint2*)(memb + (size_t)slot*256))[lane];
    a0 += wg*bf2f((u16)(mv.x & 0xFFFFu));
    a1 += wg*bf2f((u16)(mv.x >> 16));
    a2 += wg*bf2f((u16)(mv.y & 0xFFFFu));
    a3 += wg*bf2f((u16)(mv.y >> 16));
  }
  float inv = 1.f/den;
  uint32_t o0 = (uint32_t)f2bf(a0*inv) | ((uint32_t)f2bf(a1*inv) << 16);
  uint32_t o1 = (uint32_t)f2bf(a2*inv) | ((uint32_t)f2bf(a3*inv) << 16);
  ((uint2*)(att + tok*256))[lane] = make_uint2(o0, o1);
}

// ---------------- K4+K5 fused: att @ wo + bo -> LN(1024) -> GELU(tanh) -> out fp32 ----------------
// 64 tokens x 1024 cols, 1024 threads (16 waves), 64x64 wave tile (4m x 4n).
// R1 post-mortem fixes:
//  (a) store loop reordered n-innermost: each (m,r) issues 4 consecutive 64B stores
//      covering 256 contiguous bytes -> full 128B L2 lines assembled back-to-back
//      (R1 had the two halves of each line 16 stores apart -> half-dirty evictions,
//       WRITE_SIZE 133->219 MB).
//  (b) nontemporal stores for out: the 128 MB write-once stream no longer allocates
//      in L2, so woB (512 KB) stays L2-resident (R1: FETCH 12.5->42 MB from woB
//      evictions by the write stream).
__global__ __launch_bounds__(1024, 4) void k_out(
    const u16* __restrict__ A, const u16* __restrict__ woB, const float* __restrict__ bo,
    const float* __restrict__ go, const float* __restrict__ beo, float* __restrict__ out)
{
  __shared__ u16 Asl[64*256];          // 32 KB swizzled A copy
  __shared__ float red1[16*65];        // per-wave LN partial sums (stride-65 pad)
  __shared__ float red2[16*65];        // per-wave LN partial sum-of-squares

  const int tid = threadIdx.x;
  const int lane = tid & 63, w = tid >> 6;   // w = column-group: cols [w*64, w*64+64)
  const int l15 = lane & 15, l4 = lane >> 4;
  const int bm = blockIdx.x;

  #pragma unroll
  for (int j=0; j<2; ++j){
    int idx = j*1024 + tid;
    int row = idx >> 5, ch = idx & 31;
    int gc = (ch & 24) | ((ch & 7) ^ (row & 7));
    uint4 v = *(const uint4*)(A + (size_t)(bm*64 + row)*256 + gc*8);
    *(uint4*)&Asl[row*256 + ch*8] = v;
  }
  __syncthreads();

  f32x4 acc[4][4];   // [m-tile][n-tile]
  #pragma unroll
  for (int m=0; m<4; ++m)
    #pragma unroll
    for (int n=0; n<4; ++n) acc[m][n] = (f32x4){0.f,0.f,0.f,0.f};

  #pragma unroll
  for (int kt=0; kt<8; ++kt){
    const int c = kt*4 + l4;
    short8v af[4];
    #pragma unroll
    for (int m=0; m<4; ++m){
      int arow = m*16 + l15;
      int aphys = (c & 24) | ((c & 7) ^ (arow & 7));
      af[m] = *(const short8v*)&Asl[arow*256 + aphys*8];
    }
    // woB fragment-linear: fragment (kt, ct) at (kt*64 + ct)*512; this wave uses ct = w*4..w*4+3
    const u16* bbase = woB + ((size_t)kt*64 + w*4)*512 + lane*8;
    #pragma unroll
    for (int n=0; n<4; ++n){
      short8v bf = *(const short8v*)(bbase + n*512);
      #pragma unroll
      for (int m=0; m<4; ++m)
        acc[m][n] = __builtin_amdgcn_mfma_f32_16x16x32_bf16(af[m], bf, acc[m][n], 0, 0, 0);
    }
  }

  float bor[4];
  #pragma unroll
  for (int n=0; n<4; ++n) bor[n] = bo[w*64 + n*16 + l15];

  // per-(m,r) row partials over this wave's 64 columns
  float s1[4][4], s2[4][4];
  #pragma unroll
  for (int m=0; m<4; ++m)
    #pragma unroll
    for (int r=0; r<4; ++r){ s1[m][r] = 0.f; s2[m][r] = 0.f; }
  #pragma unroll
  for (int m=0; m<4; ++m)
    #pragma unroll
    for (int n=0; n<4; ++n)
      #pragma unroll
      for (int r=0; r<4; ++r){
        float v = acc[m][n][r] + bor[n];
        acc[m][n][r] = v;
        s1[m][r] += v; s2[m][r] += v*v;
      }
  #pragma unroll
  for (int m=0; m<4; ++m)
    #pragma unroll
    for (int r=0; r<4; ++r){
      #pragma unroll
      for (int msk=1; msk<16; msk<<=1){
        s1[m][r] += __shfl_xor(s1[m][r], msk);
        s2[m][r] += __shfl_xor(s2[m][r], msk);
      }
    }
  if (l15 == 0){
    #pragma unroll
    for (int m=0; m<4; ++m)
      #pragma unroll
      for (int r=0; r<4; ++r){
        int t = m*16 + l4*4 + r;
        red1[w*65 + t] = s1[m][r];
        red2[w*65 + t] = s2[m][r];
      }
  }
  __syncthreads();

  // combine 16 wave-partials per row: lane l15 holds wave-l15's partial, shfl-reduce
  float mean[4][4], rs[4][4];
  #pragma unroll
  for (int m=0; m<4; ++m)
    #pragma unroll
    for (int r=0; r<4; ++r){
      int t = m*16 + l4*4 + r;
      float a1 = red1[l15*65 + t];
      float a2 = red2[l15*65 + t];
      #pragma unroll
      for (int msk=1; msk<16; msk<<=1){
        a1 += __shfl_xor(a1, msk);
        a2 += __shfl_xor(a2, msk);
      }
      float mu = a1 * (1.f/1024.f);
      float var = a2 * (1.f/1024.f) - mu*mu;
      mean[m][r] = mu;
      rs[m][r] = rsqrtf(var + 1e-5f);
    }

  // epilogue: n INNERMOST (256B contiguous per (m,r)), nontemporal stores
  float gor[4], eor[4];
  #pragma unroll
  for (int n=0; n<4; ++n){
    int col = w*64 + n*16 + l15;
    gor[n] = go[col]; eor[n] = beo[col];
  }
  #pragma unroll
  for (int m=0; m<4; ++m)
    #pragma unroll
    for (int r=0; r<4; ++r){
      size_t row = (size_t)bm*64 + m*16 + l4*4 + r;
      float* op = out + row*1024 + w*64 + l15;
      float mu = mean[m][r], rv = rs[m][r];
      #pragma unroll
      for (int n=0; n<4; ++n){
        float v = gelu_t((acc[m][n][r] - mu)*rv*gor[n] + eor[n]);
        __builtin_nontemporal_store(v, op + n*16);
      }
    }
}

extern "C" void kernel_launch(void* const* d_in, const int* in_sizes, int n_in,
                              void* d_out, int out_size, void* d_ws, size_t ws_size,
                              hipStream_t stream) {
  const float* x    = (const float*)d_in[0];
  const float* w1   = (const float*)d_in[1];
  const float* b1   = (const float*)d_in[2];
  const float* g1   = (const float*)d_in[3];
  const float* be1  = (const float*)d_in[4];
  const float* wa   = (const float*)d_in[5];
  const float* ba   = (const float*)d_in[6];
  const float* wb   = (const float*)d_in[7];
  const float* bb   = (const float*)d_in[8];
  const float* mem  = (const float*)d_in[9];
  const float* pos  = (const float*)d_in[10];
  const float* curv = (const float*)d_in[11];
  const float* alpha= (const float*)d_in[12];
  const float* wo   = (const float*)d_in[13];
  const float* bo   = (const float*)d_in[14];
  const float* go   = (const float*)d_in[15];
  const float* beo  = (const float*)d_in[16];
  float* out = (float*)d_out;

  char* ws = (char*)d_ws;
  size_t o = 0;
  auto take = [&](size_t b) -> char* { char* p = ws + o; o += (b + 255) & ~(size_t)255; return p; };
  char*  regA   = take(67108864);
  float* hbuf48 = (float*)regA;
  float* hbuf64 = (float*)(regA + 6291456);
  float* q2b    = (float*)(regA + 6291456 + 8388608);
  u16*   att    = (u16*)take(16777216);
  u16*   w1s    = (u16*)take(196608);
  u16*   wah    = (u16*)take(32768);
  u16*   wbh    = (u16*)take(24576);
  float2* mnw   = (float2*)take(4096);
  u16*   memb   = (u16*)take(262144);
  u16*   woB    = (u16*)take(524288);
  u16*   posB   = (u16*)take(131072);
  uint32_t* glist = (uint32_t*)take(4194304);

  hipFuncSetAttribute((const void*)k_ode, hipFuncAttributeMaxDynamicSharedMemorySize, 98304);
  hipFuncSetAttribute((const void*)k_proj, hipFuncAttributeMaxDynamicSharedMemorySize, 73728);

  k_prep<<<1914, 256, 0, stream>>>(w1, wa, wb, pos, curv, mem, wo, alpha,
                                   w1s, wah, wbh, mnw, memb, woB, posB);
  k_proj<<<512, 256, 73728, stream>>>(x, w1s, b1, g1, be1, hbuf48);
  k_ode<<<256, 256, 98304, stream>>>(hbuf48, wah, wbh, ba, bb, hbuf64, q2b);
  k_sel<<<1024, 256, 0, stream>>>(hbuf64, q2b, posB, mnw, glist);
  k_attend<<<8192, 256, 0, stream>>>(glist, memb, att);
  k_out<<<512, 1024, 0, stream>>>(att, woB, bo, go, beo, out);
  (void)in_sizes; (void)n_in; (void)out_size; (void)ws_size;
}